// Round 1
// baseline (1376.098 us; speedup 1.0000x reference)
//
#include <hip/hip_runtime.h>
#include <hip/hip_bf16.h>
#include <stdint.h>

// Problem constants
#define B_   2
#define S_   2048
#define D_   1024
#define H_   16
#define BH_  32        // B*H
#define M_   4096      // B*S
#define PROBS_OFF 4194304ll   // B*S*D

typedef __attribute__((ext_vector_type(8))) short short8;   // 8 bf16 bit-patterns (4 VGPR)
typedef __attribute__((ext_vector_type(4))) float f32x4;

// ---------- bf16 split helpers (manual RNE, no API dependence) ----------
__device__ __forceinline__ short f2bf(float x) {
    uint32_t b = __float_as_uint(x);
    uint32_t r = (b + 0x7FFFu + ((b >> 16) & 1u)) >> 16;
    return (short)r;
}
__device__ __forceinline__ float bf2f(short s) {
    return __uint_as_float(((uint32_t)(uint16_t)s) << 16);
}
__device__ __forceinline__ void split2(float x, short& hi, short& lo) {
    hi = f2bf(x);
    float r = x - bf2f(hi);   // exact in fp32
    lo = f2bf(r);
}

// ---------- K0: fp32 -> (hi,lo) bf16 split ----------
__global__ __launch_bounds__(256) void k_split(const float* __restrict__ src,
                                               short* __restrict__ hi,
                                               short* __restrict__ lo, int n4) {
    int i = blockIdx.x * 256 + threadIdx.x;
    if (i >= n4) return;
    float4 v = reinterpret_cast<const float4*>(src)[i];
    short h0,l0,h1,l1,h2,l2,h3,l3;
    split2(v.x,h0,l0); split2(v.y,h1,l1); split2(v.z,h2,l2); split2(v.w,h3,l3);
    reinterpret_cast<short4*>(hi)[i] = make_short4(h0,h1,h2,h3);
    reinterpret_cast<short4*>(lo)[i] = make_short4(l0,l1,l2,l3);
}

// ---------- K1/K3: split-bf16 GEMM  C[M=4096][N=1024] = A * B^T ----------
// A [4096][1024] (k-contig), B [1024][1024] (k-contig, i.e. torch Linear weight)
// MODE 0: store Q/K as [b][h][s][64] split-bf16
// MODE 2: store V   as [b][h][dv][s] split-bf16 (transposed, packed 4-along-s)
// MODE 3: fp32 out + residual (fc layer)
template<int MODE>
__global__ __launch_bounds__(256) void k_gemm(
    const short* __restrict__ Ahi, const short* __restrict__ Alo,
    const short* __restrict__ Bhi, const short* __restrict__ Blo,
    short* __restrict__ Ohi, short* __restrict__ Olo,
    const float* __restrict__ resid, float* __restrict__ Of)
{
    const int tid = threadIdx.x, w = tid >> 6, lane = tid & 63;
    const int lq = lane & 15, g = lane >> 4;
    const int mbase = blockIdx.y * 128 + (w >> 1) * 64;
    const int nbase = blockIdx.x * 128 + (w & 1) * 64;

    f32x4 acc[4][4];
    #pragma unroll
    for (int i = 0; i < 4; ++i)
        #pragma unroll
        for (int j = 0; j < 4; ++j) acc[i][j] = (f32x4){0.f,0.f,0.f,0.f};

    for (int k0 = 0; k0 < 1024; k0 += 32) {
        short8 ah[4], al[4], bh[4], bl[4];
        #pragma unroll
        for (int mg = 0; mg < 4; ++mg) {
            size_t off = (size_t)(mbase + mg*16 + lq) * 1024 + k0 + g*8;
            ah[mg] = *reinterpret_cast<const short8*>(Ahi + off);
            al[mg] = *reinterpret_cast<const short8*>(Alo + off);
        }
        #pragma unroll
        for (int ng = 0; ng < 4; ++ng) {
            size_t off = (size_t)(nbase + ng*16 + lq) * 1024 + k0 + g*8;
            bh[ng] = *reinterpret_cast<const short8*>(Bhi + off);
            bl[ng] = *reinterpret_cast<const short8*>(Blo + off);
        }
        #pragma unroll
        for (int mg = 0; mg < 4; ++mg)
            #pragma unroll
            for (int ng = 0; ng < 4; ++ng) {
                acc[mg][ng] = __builtin_amdgcn_mfma_f32_16x16x32_bf16(ah[mg], bh[ng], acc[mg][ng], 0,0,0);
                acc[mg][ng] = __builtin_amdgcn_mfma_f32_16x16x32_bf16(ah[mg], bl[ng], acc[mg][ng], 0,0,0);
                acc[mg][ng] = __builtin_amdgcn_mfma_f32_16x16x32_bf16(al[mg], bh[ng], acc[mg][ng], 0,0,0);
            }
    }

    if constexpr (MODE == 3) {
        #pragma unroll
        for (int mg = 0; mg < 4; ++mg)
            #pragma unroll
            for (int ng = 0; ng < 4; ++ng) {
                int n = nbase + ng*16 + lq;
                #pragma unroll
                for (int r = 0; r < 4; ++r) {
                    int m = mbase + mg*16 + g*4 + r;
                    size_t ix = (size_t)m * 1024 + n;
                    Of[ix] = acc[mg][ng][r] + resid[ix];
                }
            }
    } else if constexpr (MODE == 2) {
        #pragma unroll
        for (int mg = 0; mg < 4; ++mg)
            #pragma unroll
            for (int ng = 0; ng < 4; ++ng) {
                int n = nbase + ng*16 + lq;
                int hh = n >> 6, dv = n & 63;
                int m0 = mbase + mg*16 + g*4;
                int bb = m0 >> 11, ss = m0 & 2047;      // ss multiple of 4 -> 8B aligned
                size_t idx = (((size_t)bb*16 + hh)*64 + dv) * 2048 + ss;
                uint64_t ph = 0, pl = 0;
                #pragma unroll
                for (int r = 0; r < 4; ++r) {
                    short hbv, lbv; split2(acc[mg][ng][r], hbv, lbv);
                    ph |= (uint64_t)(uint16_t)hbv << (16*r);
                    pl |= (uint64_t)(uint16_t)lbv << (16*r);
                }
                *reinterpret_cast<uint64_t*>(Ohi + idx) = ph;
                *reinterpret_cast<uint64_t*>(Olo + idx) = pl;
            }
    } else {
        #pragma unroll
        for (int mg = 0; mg < 4; ++mg)
            #pragma unroll
            for (int ng = 0; ng < 4; ++ng) {
                int n = nbase + ng*16 + lq;
                int hh = n >> 6, dk = n & 63;
                #pragma unroll
                for (int r = 0; r < 4; ++r) {
                    int m = mbase + mg*16 + g*4 + r;
                    int bb = m >> 11, ss = m & 2047;
                    size_t idx = (((size_t)bb*16 + hh)*2048 + ss) * 64 + dk;
                    short hbv, lbv; split2(acc[mg][ng][r], hbv, lbv);
                    Ohi[idx] = hbv; Olo[idx] = lbv;
                }
            }
    }
}

// ---------- K2: fused causal attention (two-pass online softmax) ----------
// Q,K: [bh][s][64] split-bf16.  V: [bh][dv][s] split-bf16 (transposed).
// Writes probs [bh][s][s] fp32 (incl. zeros above diagonal) and qkv [m][1024] split-bf16.
__global__ __launch_bounds__(256) void k_attn(
    const short* __restrict__ Qhi, const short* __restrict__ Qlo,
    const short* __restrict__ Khi, const short* __restrict__ Klo,
    const short* __restrict__ Vhi, const short* __restrict__ Vlo,
    short* __restrict__ qkvhi, short* __restrict__ qkvlo,
    float* __restrict__ probs)
{
    __shared__ __align__(16) short Ph[4][16][80];   // per-wave P tile, padded row=160B
    __shared__ __align__(16) short Pl[4][16][80];

    // XCD swizzle: 1024 blocks, 8 XCDs -> 128 consecutive work items per XCD
    int flat = blockIdx.x;
    int swz  = (flat & 7) * 128 + (flat >> 3);
    int bh = swz >> 5;            // 0..31
    int qt = swz & 31;            // q-tile index, 64 rows each

    const int tid = threadIdx.x, w = tid >> 6, lane = tid & 63;
    const int lq = lane & 15, g = lane >> 4;
    const int qbase = qt*64 + w*16;
    const int qrow  = qbase + lq;                 // this lane's q row (swapped layout)
    const size_t kvbase = (size_t)bh * S_ * 64;   // base for Q,K [bh][s][64] and V [bh][64][s]

    // Q B-fragments (held for whole kernel): B[dk][q], col=lq=q, kk=g*8+j
    short8 qbh[2], qbl[2];
    {
        size_t off = kvbase + (size_t)qrow * 64 + g*8;
        qbh[0] = *reinterpret_cast<const short8*>(Qhi + off);
        qbh[1] = *reinterpret_cast<const short8*>(Qhi + off + 32);
        qbl[0] = *reinterpret_cast<const short8*>(Qlo + off);
        qbl[1] = *reinterpret_cast<const short8*>(Qlo + off + 32);
    }

    // scores for one 64-k tile: sv[16] = s(kt*64 + f*16 + g*4 + r) for this lane's q row
    auto scores = [&](int kt, float* sv) {
        short8 kfh[4][2], kfl[4][2];
        #pragma unroll
        for (int f = 0; f < 4; ++f)
            #pragma unroll
            for (int c = 0; c < 2; ++c) {
                size_t off = kvbase + (size_t)(kt*64 + f*16 + lq) * 64 + c*32 + g*8;
                kfh[f][c] = *reinterpret_cast<const short8*>(Khi + off);
                kfl[f][c] = *reinterpret_cast<const short8*>(Klo + off);
            }
        f32x4 sa[4];
        #pragma unroll
        for (int f = 0; f < 4; ++f) sa[f] = (f32x4){0.f,0.f,0.f,0.f};
        #pragma unroll
        for (int f = 0; f < 4; ++f)
            #pragma unroll
            for (int c = 0; c < 2; ++c) {
                sa[f] = __builtin_amdgcn_mfma_f32_16x16x32_bf16(kfh[f][c], qbh[c], sa[f], 0,0,0);
                sa[f] = __builtin_amdgcn_mfma_f32_16x16x32_bf16(kfh[f][c], qbl[c], sa[f], 0,0,0);
                sa[f] = __builtin_amdgcn_mfma_f32_16x16x32_bf16(kfl[f][c], qbh[c], sa[f], 0,0,0);
            }
        #pragma unroll
        for (int f = 0; f < 4; ++f)
            #pragma unroll
            for (int r = 0; r < 4; ++r) {
                int k = kt*64 + f*16 + g*4 + r;
                float s = sa[f][r] * 0.125f;          // 1/sqrt(64)
                sv[f*4 + r] = (k <= qrow) ? s : -3e38f;
            }
    };

    // ---- pass 1: per-lane running max / sum over this lane's k-subset
    float mrun = -3e38f, lrun = 0.f;
    for (int kt = 0; kt <= qt; ++kt) {
        float sv[16];
        scores(kt, sv);
        float tmax = sv[0];
        #pragma unroll
        for (int i = 1; i < 16; ++i) tmax = fmaxf(tmax, sv[i]);
        if (tmax > mrun) { lrun *= __expf(mrun - tmax); mrun = tmax; }
        float ls = 0.f;
        #pragma unroll
        for (int i = 0; i < 16; ++i)
            if (sv[i] > -1e37f) ls += __expf(sv[i] - mrun);
        lrun += ls;
    }
    // combine the 4 lane-groups (bits 4,5) -> full-row stats on every lane
    #pragma unroll
    for (int mk = 16; mk <= 32; mk <<= 1) {
        float mo = __shfl_xor(mrun, mk);
        float lo2 = __shfl_xor(lrun, mk);
        float mn = fmaxf(mrun, mo);
        float e1 = (mrun > -1e37f) ? __expf(mrun - mn) : 0.f;
        float e2 = (mo   > -1e37f) ? __expf(mo   - mn) : 0.f;
        lrun = lrun * e1 + lo2 * e2;
        mrun = mn;
    }
    const float rli = 1.f / lrun;   // every row has >=1 valid k (k=0)

    // ---- pass 2: probs out + PV accumulate
    f32x4 oacc[4];
    #pragma unroll
    for (int fd = 0; fd < 4; ++fd) oacc[fd] = (f32x4){0.f,0.f,0.f,0.f};
    const size_t pbase = ((size_t)bh * S_ + qrow) * S_;

    for (int kt = 0; kt <= qt; ++kt) {
        float sv[16];
        scores(kt, sv);
        #pragma unroll
        for (int f = 0; f < 4; ++f) {
            float p0 = (sv[f*4+0] > -1e37f) ? __expf(sv[f*4+0] - mrun) * rli : 0.f;
            float p1 = (sv[f*4+1] > -1e37f) ? __expf(sv[f*4+1] - mrun) * rli : 0.f;
            float p2 = (sv[f*4+2] > -1e37f) ? __expf(sv[f*4+2] - mrun) * rli : 0.f;
            float p3 = (sv[f*4+3] > -1e37f) ? __expf(sv[f*4+3] - mrun) * rli : 0.f;
            *reinterpret_cast<float4*>(probs + pbase + kt*64 + f*16 + g*4) =
                make_float4(p0, p1, p2, p3);
            short h0,l0,h1,l1,h2,l2,h3,l3;
            split2(p0,h0,l0); split2(p1,h1,l1); split2(p2,h2,l2); split2(p3,h3,l3);
            uint64_t ph = (uint64_t)(uint16_t)h0 | ((uint64_t)(uint16_t)h1<<16)
                        | ((uint64_t)(uint16_t)h2<<32) | ((uint64_t)(uint16_t)h3<<48);
            uint64_t plw = (uint64_t)(uint16_t)l0 | ((uint64_t)(uint16_t)l1<<16)
                        | ((uint64_t)(uint16_t)l2<<32) | ((uint64_t)(uint16_t)l3<<48);
            *reinterpret_cast<uint64_t*>(&Ph[w][lq][f*16 + g*4]) = ph;
            *reinterpret_cast<uint64_t*>(&Pl[w][lq][f*16 + g*4]) = plw;
        }
        __syncthreads();
        #pragma unroll
        for (int c = 0; c < 2; ++c) {
            short8 pah = *reinterpret_cast<const short8*>(&Ph[w][lq][c*32 + g*8]);
            short8 pal = *reinterpret_cast<const short8*>(&Pl[w][lq][c*32 + g*8]);
            #pragma unroll
            for (int fd = 0; fd < 4; ++fd) {
                size_t voff = kvbase + (size_t)(fd*16 + lq) * 2048 + kt*64 + c*32 + g*8;
                short8 vbh = *reinterpret_cast<const short8*>(Vhi + voff);
                short8 vbl = *reinterpret_cast<const short8*>(Vlo + voff);
                oacc[fd] = __builtin_amdgcn_mfma_f32_16x16x32_bf16(pah, vbh, oacc[fd], 0,0,0);
                oacc[fd] = __builtin_amdgcn_mfma_f32_16x16x32_bf16(pah, vbl, oacc[fd], 0,0,0);
                oacc[fd] = __builtin_amdgcn_mfma_f32_16x16x32_bf16(pal, vbh, oacc[fd], 0,0,0);
            }
        }
        __syncthreads();
    }

    // store qkv as split-bf16 [m][1024]
    {
        int hh = bh & 15, bb = bh >> 4;
        #pragma unroll
        for (int fd = 0; fd < 4; ++fd)
            #pragma unroll
            for (int r = 0; r < 4; ++r) {
                int n = hh*64 + fd*16 + lq;
                int m = bb*2048 + qbase + g*4 + r;
                size_t ix = (size_t)m * 1024 + n;
                short hbv, lbv; split2(oacc[fd][r], hbv, lbv);
                qkvhi[ix] = hbv; qkvlo[ix] = lbv;
            }
    }

    // zero-fill masked tiles (k >= (qt+1)*64) for this block's 64 rows
    int kstart = (qt + 1) * 64;
    if (kstart < S_) {
        size_t rowbase = (size_t)bh * S_ * S_ + (size_t)(qt*64) * S_;
        int n4 = (S_ - kstart) >> 2;
        float4 z = make_float4(0.f, 0.f, 0.f, 0.f);
        for (int r = 0; r < 64; ++r) {
            float* rp = probs + rowbase + (size_t)r * S_ + kstart;
            for (int c = tid; c < n4; c += 256)
                reinterpret_cast<float4*>(rp)[c] = z;
        }
    }
}

// ---------- K4: in-place row LayerNorm over D=1024 ----------
__global__ __launch_bounds__(256) void k_ln(float* __restrict__ io,
                                            const float* __restrict__ gamma,
                                            const float* __restrict__ beta) {
    int row = blockIdx.x, tid = threadIdx.x;
    size_t base = (size_t)row * 1024 + tid*4;
    float4 v = *reinterpret_cast<const float4*>(io + base);
    float s  = v.x + v.y + v.z + v.w;
    float s2 = v.x*v.x + v.y*v.y + v.z*v.z + v.w*v.w;
    #pragma unroll
    for (int mk = 1; mk < 64; mk <<= 1) { s += __shfl_xor(s, mk); s2 += __shfl_xor(s2, mk); }
    __shared__ float ps[4], ps2[4];
    if ((tid & 63) == 0) { ps[tid>>6] = s; ps2[tid>>6] = s2; }
    __syncthreads();
    s  = ps[0] + ps[1] + ps[2] + ps[3];
    s2 = ps2[0] + ps2[1] + ps2[2] + ps2[3];
    float mean = s * (1.f/1024.f);
    float var  = s2 * (1.f/1024.f) - mean*mean;
    float rstd = rsqrtf(var + 1e-5f);
    float4 gm = *reinterpret_cast<const float4*>(gamma + tid*4);
    float4 bt = *reinterpret_cast<const float4*>(beta  + tid*4);
    float4 o;
    o.x = (v.x - mean)*rstd*gm.x + bt.x;
    o.y = (v.y - mean)*rstd*gm.y + bt.y;
    o.z = (v.z - mean)*rstd*gm.z + bt.z;
    o.w = (v.w - mean)*rstd*gm.w + bt.w;
    *reinterpret_cast<float4*>(io + base) = o;
}

// ---------- launcher ----------
extern "C" void kernel_launch(void* const* d_in, const int* in_sizes, int n_in,
                              void* d_out, int out_size, void* d_ws, size_t ws_size,
                              hipStream_t stream) {
    (void)in_sizes; (void)n_in; (void)out_size; (void)ws_size;
    const float* inQ  = (const float*)d_in[0];
    const float* inK  = (const float*)d_in[1];
    const float* inV  = (const float*)d_in[2];
    // d_in[3] = attn_mask (causal, known analytically) - not read
    const float* WQ   = (const float*)d_in[4];
    const float* WK   = (const float*)d_in[5];
    const float* WV   = (const float*)d_in[6];
    const float* Wfc  = (const float*)d_in[7];
    const float* gam  = (const float*)d_in[8];
    const float* bet  = (const float*)d_in[9];

    float* out    = (float*)d_out;
    float* normed = out;                    // [4096][1024] fp32
    float* probs  = out + PROBS_OFF;        // [32][2048][2048] fp32

    // ws: persistent split tensors (68 MB)
    short* p = (short*)d_ws;
    short* Qhi = p;   p += 4194304;  short* Qlo = p;   p += 4194304;
    short* KhiW= p;   p += 4194304;  short* KloW= p;   p += 4194304;
    short* VhiW= p;   p += 4194304;  short* VloW= p;   p += 4194304;
    short* qvh = p;   p += 4194304;  short* qvl = p;   p += 4194304;
    short* Wfh = p;   p += 1048576;  short* Wfl = p;   p += 1048576;

    // transient splits live in the (not yet written) probs region of d_out
    short* sc = (short*)probs;
    short* Xqh = sc;  sc += 4194304;  short* Xql = sc;  sc += 4194304;
    short* Xkh = sc;  sc += 4194304;  short* Xkl = sc;  sc += 4194304;
    short* Xvh = sc;  sc += 4194304;  short* Xvl = sc;  sc += 4194304;
    short* Wqh = sc;  sc += 1048576;  short* Wql = sc;  sc += 1048576;
    short* Wkh = sc;  sc += 1048576;  short* Wkl = sc;  sc += 1048576;
    short* Wvh = sc;  sc += 1048576;  short* Wvl = sc;  sc += 1048576;

    // K0: splits
    k_split<<<4096, 256, 0, stream>>>(inQ, Xqh, Xql, 1048576);
    k_split<<<4096, 256, 0, stream>>>(inK, Xkh, Xkl, 1048576);
    k_split<<<4096, 256, 0, stream>>>(inV, Xvh, Xvl, 1048576);
    k_split<<<1024, 256, 0, stream>>>(WQ,  Wqh, Wql, 262144);
    k_split<<<1024, 256, 0, stream>>>(WK,  Wkh, Wkl, 262144);
    k_split<<<1024, 256, 0, stream>>>(WV,  Wvh, Wvl, 262144);
    k_split<<<1024, 256, 0, stream>>>(Wfc, Wfh, Wfl, 262144);

    // K1: projections
    dim3 gg(8, 32);
    k_gemm<0><<<gg, 256, 0, stream>>>(Xqh, Xql, Wqh, Wql, Qhi,  Qlo,  nullptr, nullptr);
    k_gemm<0><<<gg, 256, 0, stream>>>(Xkh, Xkl, Wkh, Wkl, KhiW, KloW, nullptr, nullptr);
    k_gemm<2><<<gg, 256, 0, stream>>>(Xvh, Xvl, Wvh, Wvl, VhiW, VloW, nullptr, nullptr);

    // K2: attention (overwrites entire probs region, incl. transient splits)
    k_attn<<<1024, 256, 0, stream>>>(Qhi, Qlo, KhiW, KloW, VhiW, VloW, qvh, qvl, probs);

    // K3: fc + residual -> normed region (pre-LN)
    k_gemm<3><<<gg, 256, 0, stream>>>(qvh, qvl, Wfh, Wfl, nullptr, nullptr, inQ, normed);

    // K4: LayerNorm in place
    k_ln<<<4096, 256, 0, stream>>>(normed, gam, bet);
}

// Round 3
// 1292.758 us; speedup vs baseline: 1.0645x; 1.0645x over previous
//
#include <hip/hip_runtime.h>
#include <hip/hip_bf16.h>
#include <stdint.h>

// Problem constants
#define B_   2
#define S_   2048
#define D_   1024
#define H_   16
#define BH_  32        // B*H
#define M_   4096      // B*S
#define PROBS_OFF 4194304ll   // B*S*D

typedef __attribute__((ext_vector_type(8))) short short8;   // 8 bf16 bit-patterns (4 VGPR)
typedef __attribute__((ext_vector_type(4))) float f32x4;

// ---------- bf16 split helpers (manual RNE) ----------
__device__ __forceinline__ short f2bf(float x) {
    uint32_t b = __float_as_uint(x);
    uint32_t r = (b + 0x7FFFu + ((b >> 16) & 1u)) >> 16;
    return (short)r;
}
__device__ __forceinline__ float bf2f(short s) {
    return __uint_as_float(((uint32_t)(uint16_t)s) << 16);
}
__device__ __forceinline__ void split2(float x, short& hi, short& lo) {
    hi = f2bf(x);
    float r = x - bf2f(hi);   // exact in fp32
    lo = f2bf(r);
}

// ---------- async global->LDS (16B per lane) ----------
typedef const __attribute__((address_space(1))) char ga_char;
typedef __attribute__((address_space(3))) char la_char;
__device__ __forceinline__ void gld_lds16(const void* g, void* l) {
    __builtin_amdgcn_global_load_lds((ga_char*)g, (la_char*)l, 16, 0, 0);
}

// ---------- K0: fp32 -> (hi,lo) bf16 splits, merged launches ----------
__device__ __forceinline__ void split_store(const float* s, short* h, short* l, int j) {
    float4 v = reinterpret_cast<const float4*>(s)[j];
    short h0,l0,h1,l1,h2,l2,h3,l3;
    split2(v.x,h0,l0); split2(v.y,h1,l1); split2(v.z,h2,l2); split2(v.w,h3,l3);
    reinterpret_cast<short4*>(h)[j] = make_short4(h0,h1,h2,h3);
    reinterpret_cast<short4*>(l)[j] = make_short4(l0,l1,l2,l3);
}
__global__ __launch_bounds__(256) void k_split3(
    const float* __restrict__ s0, const float* __restrict__ s1, const float* __restrict__ s2,
    short* __restrict__ h0, short* __restrict__ l0, short* __restrict__ h1,
    short* __restrict__ l1, short* __restrict__ h2, short* __restrict__ l2)
{
    int i = blockIdx.x * 256 + threadIdx.x;
    int which = i >> 20, j = i & ((1 << 20) - 1);
    const float* s = which == 0 ? s0 : which == 1 ? s1 : s2;
    short* h = which == 0 ? h0 : which == 1 ? h1 : h2;
    short* l = which == 0 ? l0 : which == 1 ? l1 : l2;
    split_store(s, h, l, j);
}
__global__ __launch_bounds__(256) void k_split4(
    const float* __restrict__ s0, const float* __restrict__ s1,
    const float* __restrict__ s2, const float* __restrict__ s3,
    short* __restrict__ h0, short* __restrict__ l0, short* __restrict__ h1, short* __restrict__ l1,
    short* __restrict__ h2, short* __restrict__ l2, short* __restrict__ h3, short* __restrict__ l3)
{
    int i = blockIdx.x * 256 + threadIdx.x;
    int which = i >> 18, j = i & ((1 << 18) - 1);
    const float* s = which == 0 ? s0 : which == 1 ? s1 : which == 2 ? s2 : s3;
    short* h = which == 0 ? h0 : which == 1 ? h1 : which == 2 ? h2 : h3;
    short* l = which == 0 ? l0 : which == 1 ? l1 : which == 2 ? l2 : l3;
    split_store(s, h, l, j);
}

// ---------- K1/K3: split-bf16 GEMM, LDS-staged, double-buffered (m97 pattern) ----------
// C[4096][1024] = A[4096][1024] * B[1024][1024]^T   (k-contiguous both)
// MODE 0: store Q/K as [b][h][s][64]; MODE 2: V as [b][h][dv][s]; MODE 3: fp32 + resid
template<int MODE>
__global__ __launch_bounds__(256) void k_gemm(
    const short* __restrict__ Ahi, const short* __restrict__ Alo,
    const short* __restrict__ Bhi, const short* __restrict__ Blo,
    short* __restrict__ Ohi, short* __restrict__ Olo,
    const float* __restrict__ resid, float* __restrict__ Of)
{
    __shared__ __align__(16) short sA[2][2][4096];   // [buf][hi/lo][128 rows x 32 shorts]
    __shared__ __align__(16) short sB[2][2][4096];

    const int tid = threadIdx.x, w = tid >> 6, lane = tid & 63;
    const int lq = lane & 15, g = lane >> 4;
    const int mtile = blockIdx.y * 128, ntile = blockIdx.x * 128;
    const int mbase = (w >> 1) * 64, nbase = (w & 1) * 64;

    const char* Ah = (const char*)Ahi + (size_t)mtile * 2048;
    const char* Al = (const char*)Alo + (size_t)mtile * 2048;
    const char* Bh = (const char*)Bhi + (size_t)ntile * 2048;
    const char* Bl = (const char*)Blo + (size_t)ntile * 2048;

    // 8KB stage: LDS[row][32 shorts] = src[row*2048B + chunk], linear LDS dest
    auto stage = [&](const char* srcbase, short* dst) {
        char* d = (char*)dst;
        #pragma unroll
        for (int i = 0; i < 2; ++i) {
            uint32_t o = (uint32_t)((i*256 + tid) * 16);
            uint32_t row = o >> 6, col = o & 63u;
            gld_lds16(srcbase + (size_t)row * 2048 + col, d + o);
        }
    };

    f32x4 acc[4][4];
    #pragma unroll
    for (int i = 0; i < 4; ++i)
        #pragma unroll
        for (int j = 0; j < 4; ++j) acc[i][j] = (f32x4){0.f,0.f,0.f,0.f};

    stage(Ah, sA[0][0]); stage(Al, sA[0][1]);
    stage(Bh, sB[0][0]); stage(Bl, sB[0][1]);

    for (int ki = 0; ki < 32; ++ki) {
        __syncthreads();                       // drains prev-issued stage (overlapped w/ compute)
        int cur = ki & 1;
        if (ki < 31) {
            size_t kb = (size_t)(ki + 1) * 64;  // 32 shorts = 64 bytes
            stage(Ah + kb, sA[cur^1][0]); stage(Al + kb, sA[cur^1][1]);
            stage(Bh + kb, sB[cur^1][0]); stage(Bl + kb, sB[cur^1][1]);
        }
        short8 ah[4], al[4], bh[4], bl[4];
        #pragma unroll
        for (int mg = 0; mg < 4; ++mg) {
            size_t a = (size_t)(mbase + mg*16 + lq) * 64 + g*16;
            ah[mg] = *reinterpret_cast<const short8*>((const char*)sA[cur][0] + a);
            al[mg] = *reinterpret_cast<const short8*>((const char*)sA[cur][1] + a);
        }
        #pragma unroll
        for (int ng = 0; ng < 4; ++ng) {
            size_t a = (size_t)(nbase + ng*16 + lq) * 64 + g*16;
            bh[ng] = *reinterpret_cast<const short8*>((const char*)sB[cur][0] + a);
            bl[ng] = *reinterpret_cast<const short8*>((const char*)sB[cur][1] + a);
        }
        #pragma unroll
        for (int mg = 0; mg < 4; ++mg)
            #pragma unroll
            for (int ng = 0; ng < 4; ++ng) {
                acc[mg][ng] = __builtin_amdgcn_mfma_f32_16x16x32_bf16(ah[mg], bh[ng], acc[mg][ng], 0,0,0);
                acc[mg][ng] = __builtin_amdgcn_mfma_f32_16x16x32_bf16(ah[mg], bl[ng], acc[mg][ng], 0,0,0);
                acc[mg][ng] = __builtin_amdgcn_mfma_f32_16x16x32_bf16(al[mg], bh[ng], acc[mg][ng], 0,0,0);
            }
    }

    const int gm0 = mtile + mbase, gn0 = ntile + nbase;
    if constexpr (MODE == 3) {
        #pragma unroll
        for (int mg = 0; mg < 4; ++mg)
            #pragma unroll
            for (int ng = 0; ng < 4; ++ng) {
                int n = gn0 + ng*16 + lq;
                #pragma unroll
                for (int r = 0; r < 4; ++r) {
                    int m = gm0 + mg*16 + g*4 + r;
                    size_t ix = (size_t)m * 1024 + n;
                    Of[ix] = acc[mg][ng][r] + resid[ix];
                }
            }
    } else if constexpr (MODE == 2) {
        #pragma unroll
        for (int mg = 0; mg < 4; ++mg)
            #pragma unroll
            for (int ng = 0; ng < 4; ++ng) {
                int n = gn0 + ng*16 + lq;
                int hh = n >> 6, dv = n & 63;
                int m0 = gm0 + mg*16 + g*4;
                int bb = m0 >> 11, ss = m0 & 2047;
                size_t idx = (((size_t)bb*16 + hh)*64 + dv) * 2048 + ss;
                uint64_t ph = 0, pl = 0;
                #pragma unroll
                for (int r = 0; r < 4; ++r) {
                    short hbv, lbv; split2(acc[mg][ng][r], hbv, lbv);
                    ph |= (uint64_t)(uint16_t)hbv << (16*r);
                    pl |= (uint64_t)(uint16_t)lbv << (16*r);
                }
                *reinterpret_cast<uint64_t*>(Ohi + idx) = ph;
                *reinterpret_cast<uint64_t*>(Olo + idx) = pl;
            }
    } else {
        #pragma unroll
        for (int mg = 0; mg < 4; ++mg)
            #pragma unroll
            for (int ng = 0; ng < 4; ++ng) {
                int n = gn0 + ng*16 + lq;
                int hh = n >> 6, dk = n & 63;
                #pragma unroll
                for (int r = 0; r < 4; ++r) {
                    int m = gm0 + mg*16 + g*4 + r;
                    int bb = m >> 11, ss = m & 2047;
                    size_t idx = (((size_t)bb*16 + hh)*2048 + ss) * 64 + dk;
                    short hbv, lbv; split2(acc[mg][ng][r], hbv, lbv);
                    Ohi[idx] = hbv; Olo[idx] = lbv;
                }
            }
    }
}

// ---------- K2: fused causal attention (round-1 proven version, direct global reads) ----------
// Q,K: [bh][s][64] split-bf16.  V: [bh][dv][s] split-bf16 (transposed).
// Writes probs [bh][s][s] fp32 (incl. zeros above diagonal) and qkv [m][1024] split-bf16.
__global__ __launch_bounds__(256) void k_attn(
    const short* __restrict__ Qhi, const short* __restrict__ Qlo,
    const short* __restrict__ Khi, const short* __restrict__ Klo,
    const short* __restrict__ Vhi, const short* __restrict__ Vlo,
    short* __restrict__ qkvhi, short* __restrict__ qkvlo,
    float* __restrict__ probs)
{
    __shared__ __align__(16) short Ph[4][16][80];   // per-wave P tile, padded row=160B
    __shared__ __align__(16) short Pl[4][16][80];

    // XCD swizzle: 1024 blocks, 8 XCDs -> 128 consecutive work items per XCD
    int flat = blockIdx.x;
    int swz  = (flat & 7) * 128 + (flat >> 3);
    int bh = swz >> 5;            // 0..31
    int qt = swz & 31;            // q-tile index, 64 rows each

    const int tid = threadIdx.x, w = tid >> 6, lane = tid & 63;
    const int lq = lane & 15, g = lane >> 4;
    const int qbase = qt*64 + w*16;
    const int qrow  = qbase + lq;                 // this lane's q row (swapped layout)
    const size_t kvbase = (size_t)bh * S_ * 64;   // base for Q,K [bh][s][64] and V [bh][64][s]

    // Q B-fragments (held for whole kernel): B[dk][q], col=lq=q, kk=g*8+j
    short8 qbh[2], qbl[2];
    {
        size_t off = kvbase + (size_t)qrow * 64 + g*8;
        qbh[0] = *reinterpret_cast<const short8*>(Qhi + off);
        qbh[1] = *reinterpret_cast<const short8*>(Qhi + off + 32);
        qbl[0] = *reinterpret_cast<const short8*>(Qlo + off);
        qbl[1] = *reinterpret_cast<const short8*>(Qlo + off + 32);
    }

    // scores for one 64-k tile: sv[16] = s(kt*64 + f*16 + g*4 + r) for this lane's q row
    auto scores = [&](int kt, float* sv) {
        short8 kfh[4][2], kfl[4][2];
        #pragma unroll
        for (int f = 0; f < 4; ++f)
            #pragma unroll
            for (int c = 0; c < 2; ++c) {
                size_t off = kvbase + (size_t)(kt*64 + f*16 + lq) * 64 + c*32 + g*8;
                kfh[f][c] = *reinterpret_cast<const short8*>(Khi + off);
                kfl[f][c] = *reinterpret_cast<const short8*>(Klo + off);
            }
        f32x4 sa[4];
        #pragma unroll
        for (int f = 0; f < 4; ++f) sa[f] = (f32x4){0.f,0.f,0.f,0.f};
        #pragma unroll
        for (int f = 0; f < 4; ++f)
            #pragma unroll
            for (int c = 0; c < 2; ++c) {
                sa[f] = __builtin_amdgcn_mfma_f32_16x16x32_bf16(kfh[f][c], qbh[c], sa[f], 0,0,0);
                sa[f] = __builtin_amdgcn_mfma_f32_16x16x32_bf16(kfh[f][c], qbl[c], sa[f], 0,0,0);
                sa[f] = __builtin_amdgcn_mfma_f32_16x16x32_bf16(kfl[f][c], qbh[c], sa[f], 0,0,0);
            }
        #pragma unroll
        for (int f = 0; f < 4; ++f)
            #pragma unroll
            for (int r = 0; r < 4; ++r) {
                int k = kt*64 + f*16 + g*4 + r;
                float s = sa[f][r] * 0.125f;          // 1/sqrt(64)
                sv[f*4 + r] = (k <= qrow) ? s : -3e38f;
            }
    };

    // ---- pass 1: per-lane running max / sum over this lane's k-subset
    float mrun = -3e38f, lrun = 0.f;
    for (int kt = 0; kt <= qt; ++kt) {
        float sv[16];
        scores(kt, sv);
        float tmax = sv[0];
        #pragma unroll
        for (int i = 1; i < 16; ++i) tmax = fmaxf(tmax, sv[i]);
        if (tmax > mrun) { lrun *= __expf(mrun - tmax); mrun = tmax; }
        float ls = 0.f;
        #pragma unroll
        for (int i = 0; i < 16; ++i)
            if (sv[i] > -1e37f) ls += __expf(sv[i] - mrun);
        lrun += ls;
    }
    // combine the 4 lane-groups (bits 4,5) -> full-row stats on every lane
    #pragma unroll
    for (int mk = 16; mk <= 32; mk <<= 1) {
        float mo = __shfl_xor(mrun, mk);
        float lo2 = __shfl_xor(lrun, mk);
        float mn = fmaxf(mrun, mo);
        float e1 = (mrun > -1e37f) ? __expf(mrun - mn) : 0.f;
        float e2 = (mo   > -1e37f) ? __expf(mo   - mn) : 0.f;
        lrun = lrun * e1 + lo2 * e2;
        mrun = mn;
    }
    const float rli = 1.f / lrun;   // every row has >=1 valid k (k=0)

    // ---- pass 2: probs out + PV accumulate
    f32x4 oacc[4];
    #pragma unroll
    for (int fd = 0; fd < 4; ++fd) oacc[fd] = (f32x4){0.f,0.f,0.f,0.f};
    const size_t pbase = ((size_t)bh * S_ + qrow) * S_;

    for (int kt = 0; kt <= qt; ++kt) {
        float sv[16];
        scores(kt, sv);
        #pragma unroll
        for (int f = 0; f < 4; ++f) {
            float p0 = (sv[f*4+0] > -1e37f) ? __expf(sv[f*4+0] - mrun) * rli : 0.f;
            float p1 = (sv[f*4+1] > -1e37f) ? __expf(sv[f*4+1] - mrun) * rli : 0.f;
            float p2 = (sv[f*4+2] > -1e37f) ? __expf(sv[f*4+2] - mrun) * rli : 0.f;
            float p3 = (sv[f*4+3] > -1e37f) ? __expf(sv[f*4+3] - mrun) * rli : 0.f;
            *reinterpret_cast<float4*>(probs + pbase + kt*64 + f*16 + g*4) =
                make_float4(p0, p1, p2, p3);
            short h0,l0,h1,l1,h2,l2,h3,l3;
            split2(p0,h0,l0); split2(p1,h1,l1); split2(p2,h2,l2); split2(p3,h3,l3);
            uint64_t ph = (uint64_t)(uint16_t)h0 | ((uint64_t)(uint16_t)h1<<16)
                        | ((uint64_t)(uint16_t)h2<<32) | ((uint64_t)(uint16_t)h3<<48);
            uint64_t plw = (uint64_t)(uint16_t)l0 | ((uint64_t)(uint16_t)l1<<16)
                        | ((uint64_t)(uint16_t)l2<<32) | ((uint64_t)(uint16_t)l3<<48);
            *reinterpret_cast<uint64_t*>(&Ph[w][lq][f*16 + g*4]) = ph;
            *reinterpret_cast<uint64_t*>(&Pl[w][lq][f*16 + g*4]) = plw;
        }
        __syncthreads();
        #pragma unroll
        for (int c = 0; c < 2; ++c) {
            short8 pah = *reinterpret_cast<const short8*>(&Ph[w][lq][c*32 + g*8]);
            short8 pal = *reinterpret_cast<const short8*>(&Pl[w][lq][c*32 + g*8]);
            #pragma unroll
            for (int fd = 0; fd < 4; ++fd) {
                size_t voff = kvbase + (size_t)(fd*16 + lq) * 2048 + kt*64 + c*32 + g*8;
                short8 vbh = *reinterpret_cast<const short8*>(Vhi + voff);
                short8 vbl = *reinterpret_cast<const short8*>(Vlo + voff);
                oacc[fd] = __builtin_amdgcn_mfma_f32_16x16x32_bf16(pah, vbh, oacc[fd], 0,0,0);
                oacc[fd] = __builtin_amdgcn_mfma_f32_16x16x32_bf16(pah, vbl, oacc[fd], 0,0,0);
                oacc[fd] = __builtin_amdgcn_mfma_f32_16x16x32_bf16(pal, vbh, oacc[fd], 0,0,0);
            }
        }
        __syncthreads();
    }

    // store qkv as split-bf16 [m][1024]
    {
        int hh = bh & 15, bb = bh >> 4;
        #pragma unroll
        for (int fd = 0; fd < 4; ++fd)
            #pragma unroll
            for (int r = 0; r < 4; ++r) {
                int n = hh*64 + fd*16 + lq;
                int m = bb*2048 + qbase + g*4 + r;
                size_t ix = (size_t)m * 1024 + n;
                short hbv, lbv; split2(oacc[fd][r], hbv, lbv);
                qkvhi[ix] = hbv; qkvlo[ix] = lbv;
            }
    }

    // zero-fill masked tiles (k >= (qt+1)*64) for this block's 64 rows
    int kstart = (qt + 1) * 64;
    if (kstart < S_) {
        size_t rowbase = (size_t)bh * S_ * S_ + (size_t)(qt*64) * S_;
        int n4 = (S_ - kstart) >> 2;
        float4 z = make_float4(0.f, 0.f, 0.f, 0.f);
        for (int r = 0; r < 64; ++r) {
            float* rp = probs + rowbase + (size_t)r * S_ + kstart;
            for (int c = tid; c < n4; c += 256)
                reinterpret_cast<float4*>(rp)[c] = z;
        }
    }
}

// ---------- K4: in-place row LayerNorm over D=1024 ----------
__global__ __launch_bounds__(256) void k_ln(float* __restrict__ io,
                                            const float* __restrict__ gamma,
                                            const float* __restrict__ beta) {
    int row = blockIdx.x, tid = threadIdx.x;
    size_t base = (size_t)row * 1024 + tid*4;
    float4 v = *reinterpret_cast<const float4*>(io + base);
    float s  = v.x + v.y + v.z + v.w;
    float s2 = v.x*v.x + v.y*v.y + v.z*v.z + v.w*v.w;
    #pragma unroll
    for (int mk = 1; mk < 64; mk <<= 1) { s += __shfl_xor(s, mk); s2 += __shfl_xor(s2, mk); }
    __shared__ float ps[4], ps2[4];
    if ((tid & 63) == 0) { ps[tid>>6] = s; ps2[tid>>6] = s2; }
    __syncthreads();
    s  = ps[0] + ps[1] + ps[2] + ps[3];
    s2 = ps2[0] + ps2[1] + ps2[2] + ps2[3];
    float mean = s * (1.f/1024.f);
    float var  = s2 * (1.f/1024.f) - mean*mean;
    float rstd = rsqrtf(var + 1e-5f);
    float4 gm = *reinterpret_cast<const float4*>(gamma + tid*4);
    float4 bt = *reinterpret_cast<const float4*>(beta  + tid*4);
    float4 o;
    o.x = (v.x - mean)*rstd*gm.x + bt.x;
    o.y = (v.y - mean)*rstd*gm.y + bt.y;
    o.z = (v.z - mean)*rstd*gm.z + bt.z;
    o.w = (v.w - mean)*rstd*gm.w + bt.w;
    *reinterpret_cast<float4*>(io + base) = o;
}

// ---------- launcher ----------
extern "C" void kernel_launch(void* const* d_in, const int* in_sizes, int n_in,
                              void* d_out, int out_size, void* d_ws, size_t ws_size,
                              hipStream_t stream) {
    (void)in_sizes; (void)n_in; (void)out_size; (void)ws_size;
    const float* inQ  = (const float*)d_in[0];
    const float* inK  = (const float*)d_in[1];
    const float* inV  = (const float*)d_in[2];
    // d_in[3] = attn_mask (causal, known analytically) - not read
    const float* WQ   = (const float*)d_in[4];
    const float* WK   = (const float*)d_in[5];
    const float* WV   = (const float*)d_in[6];
    const float* Wfc  = (const float*)d_in[7];
    const float* gam  = (const float*)d_in[8];
    const float* bet  = (const float*)d_in[9];

    float* out    = (float*)d_out;
    float* normed = out;                    // [4096][1024] fp32
    float* probs  = out + PROBS_OFF;        // [32][2048][2048] fp32

    // ws: persistent split tensors (68 MB)
    short* p = (short*)d_ws;
    short* Qhi = p;   p += 4194304;  short* Qlo = p;   p += 4194304;
    short* KhiW= p;   p += 4194304;  short* KloW= p;   p += 4194304;
    short* VhiW= p;   p += 4194304;  short* VloW= p;   p += 4194304;
    short* qvh = p;   p += 4194304;  short* qvl = p;   p += 4194304;
    short* Wfh = p;   p += 1048576;  short* Wfl = p;   p += 1048576;

    // transient splits live in the (not yet written) probs region of d_out
    short* sc = (short*)probs;
    short* Xqh = sc;  sc += 4194304;  short* Xql = sc;  sc += 4194304;
    short* Xkh = sc;  sc += 4194304;  short* Xkl = sc;  sc += 4194304;
    short* Xvh = sc;  sc += 4194304;  short* Xvl = sc;  sc += 4194304;
    short* Wqh = sc;  sc += 1048576;  short* Wql = sc;  sc += 1048576;
    short* Wkh = sc;  sc += 1048576;  short* Wkl = sc;  sc += 1048576;
    short* Wvh = sc;  sc += 1048576;  short* Wvl = sc;  sc += 1048576;

    // K0: splits (merged: 3 activations, 4 weights)
    k_split3<<<12288, 256, 0, stream>>>(inQ, inK, inV, Xqh, Xql, Xkh, Xkl, Xvh, Xvl);
    k_split4<<<4096, 256, 0, stream>>>(WQ, WK, WV, Wfc, Wqh, Wql, Wkh, Wkl, Wvh, Wvl, Wfh, Wfl);

    // K1: projections (LDS-staged GEMMs under validation this round)
    dim3 gg(8, 32);
    k_gemm<0><<<gg, 256, 0, stream>>>(Xqh, Xql, Wqh, Wql, Qhi,  Qlo,  nullptr, nullptr);
    k_gemm<0><<<gg, 256, 0, stream>>>(Xkh, Xkl, Wkh, Wkl, KhiW, KloW, nullptr, nullptr);
    k_gemm<2><<<gg, 256, 0, stream>>>(Xvh, Xvl, Wvh, Wvl, VhiW, VloW, nullptr, nullptr);

    // K2: attention (round-1 proven version; overwrites entire probs region)
    k_attn<<<1024, 256, 0, stream>>>(Qhi, Qlo, KhiW, KloW, VhiW, VloW, qvh, qvl, probs);

    // K3: fc + residual -> normed region (pre-LN)
    k_gemm<3><<<gg, 256, 0, stream>>>(qvh, qvl, Wfh, Wfl, nullptr, nullptr, inQ, normed);

    // K4: LayerNorm in place
    k_ln<<<4096, 256, 0, stream>>>(normed, gam, bet);
}